// Round 9
// baseline (158.633 us; speedup 1.0000x reference)
//
#include <hip/hip_runtime.h>

// fastmax linear attention (causal, p=1): chunked scan + bf16 MFMA matmuls.
// b=2, h=8, n=8192, d=32 -> bh=16, chunks of C=64 rows, 128 chunks per bh,
// 32 groups of 4 chunks per bh.  ONE launch, decoupled lookback:
//  phase A: per block (one group of 4 chunks) depth-4 register scan.  k held
//    in fp32 registers; v staged ONCE into persistent LDS vT4 (phase-C
//    layout, permuted rows).  Within-group prefixes stay in registers.
//    Writes only the group's INCLUSIVE total (gtot: bf16 KV at [np*32+d1b]
//    + fp32 ksum/vsum tail) then __threadfence + flag.
//  lookback: lanes t<g spin on the <=31 predecessor flags (all co-resident:
//    LDS 51200B -> 3 blocks/CU, grid 512 needs 2/CU), then 8-wide batched
//    gtot sum read at this thread's own (np,d1b) offset (composes with the
//    register-held prefixes -- no relayout through memory).
//  phase C: per chunk, kc_s/kbf staged from held k regs, vTbf = vT4[ci]
//    (no v re-read), q prefetched.  MFMA numerator + fp32 denominator.
// Flags zeroed by a 2KB hipMemsetAsync before the kernel (workspace is
// poisoned by the harness each iteration).

#define D      32
#define C      64
#define NCHUNK 128
#define GSIZE  4          // chunks per group == per block
#define NGROUP 32         // groups per bh
#define BH     16
#define NBLK   (BH * NCHUNK)     // 2048 chunks
#define NGRP   (NBLK / GSIZE)    // 512 blocks
#define AGGU   1152   // ushorts per gtot vector: 1024 bf16 KV + 64 fp32 tail

typedef __attribute__((ext_vector_type(8))) short bf16x8;
typedef __attribute__((ext_vector_type(4))) float f32x4;
typedef __attribute__((ext_vector_type(4))) unsigned short u16x4;

__device__ __forceinline__ unsigned short f2bf(float x) {
  union { float f; unsigned u; } c; c.f = x;
  unsigned r = (c.u + 0x7FFFu + ((c.u >> 16) & 1u)) >> 16;   // RNE
  return (unsigned short)r;
}
__device__ __forceinline__ float bf2f(unsigned short u) {
  union { unsigned u; float f; } c; c.u = ((unsigned)u) << 16;
  return c.f;
}
// MFMA output col n = original col (n<16 ? 2n : 2(n-16)+1); element with
// original col e stages at row n(e) = (e&1) ? 16+(e>>1) : (e>>1)
__device__ __forceinline__ int permcol(int e) {
  return (e & 1) ? (16 + (e >> 1)) : (e >> 1);
}

__global__ __launch_bounds__(256, 2) void fused_kernel(
    const float* __restrict__ q, const float* __restrict__ k,
    const float* __restrict__ v, unsigned short* __restrict__ gtot,
    unsigned int* __restrict__ flags, float* __restrict__ out) {
  // LDS: vT4 persists across phases; arena is time-shared A->C.
  __shared__ __align__(16) char smem[51200];
  unsigned short* vT4 = (unsigned short*)smem;              // 4x[32][72] bf16, 18432B
  char* arena = smem + 18432;                               // 32768B
  // phase A view:
  unsigned short* kT  = (unsigned short*)arena;             // [32][72], 4608B
  float* psK = (float*)(arena + 4608);                      // 4096B
  float* psV = (float*)(arena + 8704);                      // 4096B
  // phase C view:
  unsigned short* qbf = (unsigned short*)arena;             // [64][40], 5120B
  unsigned short* kbf = (unsigned short*)(arena + 5120);    // [64][40], 5120B
  float* q_s = (float*)arena;                               // [64][36] fp32 (part2+)
  unsigned short* kvTbf = (unsigned short*)(arena + 10240); // [32][40], 2560B
  unsigned short* Tbf   = (unsigned short*)(arena + 12800); // [64][72], 9216B
  float* kc_s   = (float*)(arena + 22016);                  // [64][36], 9216B
  float* gtot_s = (float*)(arena + 31232);                  // 8*32, 1024B
  float* pre_s  = (float*)(arena + 32256);                  // 64, 256B
  float* invdiv_s = (float*)(arena + 32512);                // 64, 256B

  int t  = threadIdx.x;
  int j0 = t >> 3;
  int cb = (t & 7) * 4;
  int lane = t & 63, w = t >> 6;
  int m16 = lane & 15, quad = lane >> 4;
  int mb = w >> 1, nb = w & 1;
  int d1b = 16 * mb + quad * 4;
  int np  = permcol(16 * nb + m16);
  int rg  = t >> 5;
  int e   = t & 31;
  int g   = blockIdx.x & (NGROUP - 1);
  int bh  = blockIdx.x >> 5;
  int blk0 = blockIdx.x * GSIZE;
  int myoff = np * 32 + d1b;             // this thread's 4 KV elems in gtot

  const float4* kp  = (const float4*)k + (size_t)blk0 * 512;
  const float4* vp  = (const float4*)v + (size_t)blk0 * 512;
  const float4* qp4 = (const float4*)q + (size_t)blk0 * 512;
  const unsigned short* gtb = gtot + (size_t)(bh * NGROUP) * AGGU;

  // zero Tbf early (region untouched by phase A; masked part must read 0)
  for (int z = t; z < (C * 72) / 8; z += 256)
    ((uint4*)Tbf)[z] = make_uint4(0, 0, 0, 0);

  // ======================= phase A: depth-4 scan ===========================
  float4 kHA[4], kHB[4];                 // k held fp32 for phase C
  float prefs[4][4], tails[4];           // within-group exclusive prefixes
  float pr0 = 0.f, pr1 = 0.f, pr2 = 0.f, pr3 = 0.f, tailpref = 0.f;

  kHA[0] = kp[t]; kHB[0] = kp[t + 256];
  float4 vA = vp[t], vB = vp[t + 256];

#pragma unroll
  for (int ci = 0; ci < GSIZE; ++ci) {
    unsigned short* vTc = vT4 + ci * (D * 72);
    {
      const float* ka = &kHA[ci].x; const float* kb = &kHB[ci].x;
      const float* va = &vA.x;      const float* vb = &vB.x;
#pragma unroll
      for (int cc = 0; cc < 4; ++cc) {
        kT[(cb + cc) * 72 + j0]      = f2bf(ka[cc]);
        kT[(cb + cc) * 72 + j0 + 32] = f2bf(kb[cc]);
        int n = permcol(cb + cc);    // store v permuted = phase-C layout
        vTc[n * 72 + j0]      = f2bf(va[cc]);
        vTc[n * 72 + j0 + 32] = f2bf(vb[cc]);
      }
      *(float4*)&psK[4 * t] = make_float4(kHA[ci].x + kHB[ci].x,
                                          kHA[ci].y + kHB[ci].y,
                                          kHA[ci].z + kHB[ci].z,
                                          kHA[ci].w + kHB[ci].w);
      *(float4*)&psV[4 * t] =
          make_float4(vA.x + vB.x, vA.y + vB.y, vA.z + vB.z, vA.w + vB.w);
    }
    __syncthreads();

    if (ci + 1 < GSIZE) {                // prefetch next chunk
      kHA[ci + 1] = kp[(ci + 1) * 512 + t];
      kHB[ci + 1] = kp[(ci + 1) * 512 + t + 256];
      vA = vp[(ci + 1) * 512 + t]; vB = vp[(ci + 1) * 512 + t + 256];
    }

    // KV = K^T.V (permuted vTc: read row np instead of d2 -- same data)
    f32x4 acc = {0.f, 0.f, 0.f, 0.f};
#pragma unroll
    for (int kb2 = 0; kb2 < 2; ++kb2) {
      bf16x8 a = *(const bf16x8*)&kT[(16 * mb + m16) * 72 + kb2 * 32 + quad * 8];
      bf16x8 b = *(const bf16x8*)&vTc[np * 72 + kb2 * 32 + quad * 8];
      acc = __builtin_amdgcn_mfma_f32_16x16x32_bf16(a, b, acc, 0, 0, 0);
    }
    float csum = 0.f;
    if (t < 64) {
      int ee = t & 31;
      const float* ps = (t < 32) ? psK : psV;
#pragma unroll
      for (int m = 0; m < 32; ++m) csum += ps[ee + 32 * m];
    }
    prefs[ci][0] = pr0; prefs[ci][1] = pr1;
    prefs[ci][2] = pr2; prefs[ci][3] = pr3;
    tails[ci] = tailpref;
    pr0 += acc[0]; pr1 += acc[1]; pr2 += acc[2]; pr3 += acc[3];
    tailpref += csum;
    __syncthreads();                     // protect kT/psK/psV before restage
  }

  // publish INCLUSIVE group total + flag
  {
    unsigned short* gt = gtot + (size_t)blockIdx.x * AGGU;
    *(u16x4*)&gt[myoff] =
        (u16x4){f2bf(pr0), f2bf(pr1), f2bf(pr2), f2bf(pr3)};
    if (t < 64) ((float*)(gt + 1024))[t] = tailpref;
  }
  __syncthreads();
  if (t == 0) {
    __threadfence();
    atomicExch(&flags[blockIdx.x], 1u);
  }

  // ======================= lookback: <=31 predecessor groups ===============
  float4 qA = qp4[t], qB = qp4[t + 256];   // chunk-0 q hides under the spin

  if (t < g) {                             // parallel spin, one lane per flag
    int guard = 0;
    while (atomicAdd(&flags[(bh << 5) + t], 0u) == 0u && guard < (1 << 22)) {
      __builtin_amdgcn_s_sleep(2);
      ++guard;
    }
  }
  __syncthreads();
  __threadfence();

  float gs0 = 0.f, gs1 = 0.f, gs2 = 0.f, gs3 = 0.f, gtf = 0.f;
  for (int p0 = 0; p0 < g; p0 += 8) {      // 8-wide predicated in-flight loads
    uint2 r[8]; float tl[8];
#pragma unroll
    for (int u = 0; u < 8; ++u) {
      int p = p0 + u;
      const unsigned short* gp = gtb + (size_t)(p < g ? p : 0) * AGGU;
      r[u] = *(const uint2*)&gp[myoff];    // (np,d1b) offset: matches regs!
      if (t < 64) tl[u] = ((const float*)(gp + 1024))[t];
    }
#pragma unroll
    for (int u = 0; u < 8; ++u) {
      if (p0 + u < g) {
        gs0 += bf2f((unsigned short)(r[u].x & 0xffff));
        gs1 += bf2f((unsigned short)(r[u].x >> 16));
        gs2 += bf2f((unsigned short)(r[u].y & 0xffff));
        gs3 += bf2f((unsigned short)(r[u].y >> 16));
        if (t < 64) gtf += tl[u];
      }
    }
  }

  // ======================= phase C: output, 4 chunks =======================
#pragma unroll
  for (int ci = 0; ci < GSIZE; ++ci) {
    int blk = blk0 + ci;
    int c   = blk & 127;
    size_t off = (size_t)blk * (C * D);
    const unsigned short* vTc = vT4 + ci * (D * 72);

    // ---- stage: kc_s/kbf from held regs; qbf from q; kvTbf from prefix ----
    *(float4*)&kc_s[j0 * 36 + cb]        = kHA[ci];
    *(float4*)&kc_s[(j0 + 32) * 36 + cb] = kHB[ci];
    *(u16x4*)&qbf[j0 * 40 + cb] =
        (u16x4){f2bf(qA.x), f2bf(qA.y), f2bf(qA.z), f2bf(qA.w)};
    *(u16x4*)&qbf[(j0 + 32) * 40 + cb] =
        (u16x4){f2bf(qB.x), f2bf(qB.y), f2bf(qB.z), f2bf(qB.w)};
    *(u16x4*)&kbf[j0 * 40 + cb] =
        (u16x4){f2bf(kHA[ci].x), f2bf(kHA[ci].y),
                f2bf(kHA[ci].z), f2bf(kHA[ci].w)};
    *(u16x4*)&kbf[(j0 + 32) * 40 + cb] =
        (u16x4){f2bf(kHB[ci].x), f2bf(kHB[ci].y),
                f2bf(kHB[ci].z), f2bf(kHB[ci].w)};
    {
      float s0 = gs0 + prefs[ci][0];
      float s1 = gs1 + prefs[ci][1];
      float s2 = gs2 + prefs[ci][2];
      float s3 = gs3 + prefs[ci][3];
      *(u16x4*)&kvTbf[np * 40 + d1b] =       // (np,d1b): same positions
          (u16x4){f2bf(s0), f2bf(s1), f2bf(s2), f2bf(s3)};
    }
    if (t < 64) pre_s[t] = gtf + tails[ci];
    __syncthreads();

    // ---- prefetch next chunk's q while MFMAs run --------------------------
    float4 nqA = make_float4(0, 0, 0, 0), nqB = nqA;
    if (ci + 1 < GSIZE) {
      nqA = qp4[(ci + 1) * 512 + t];
      nqB = qp4[(ci + 1) * 512 + t + 256];
    }

    // ---- part 1: S tiles -> Tbf;  k col-sum phase a -----------------------
    const bf16x8 aQ = *(const bf16x8*)&qbf[(16 * w + m16) * 40 + quad * 8];
    for (int jb = 0; jb <= w; ++jb) {
      bf16x8 bK = *(const bf16x8*)&kbf[(16 * jb + m16) * 40 + quad * 8];
      f32x4 cS = {0.f, 0.f, 0.f, 0.f};
      cS = __builtin_amdgcn_mfma_f32_16x16x32_bf16(aQ, bK, cS, 0, 0, 0);
      int jcol = 16 * jb + m16;
#pragma unroll
      for (int reg = 0; reg < 4; ++reg) {
        int i = 16 * w + quad * 4 + reg;
        float tv = (jcol <= i) ? (1.f + cS[reg]) : 0.f;
        Tbf[i * 72 + jcol] = f2bf(tv);
      }
    }
    float vals[8];
    {
      float run = 0.f;
#pragma unroll
      for (int r = 0; r < 8; ++r) {
        vals[r] = kc_s[(rg * 8 + r) * 36 + e];
        run += vals[r];
      }
      gtot_s[rg * 32 + e] = run;
    }
    __syncthreads();                     // qbf/kbf dead past this point

    // ---- part 2: group offsets + kpre -> k-cumsum; stage q_s --------------
    {
      float offv = pre_s[e];             // ksum prefix
      for (int g2 = 0; g2 < rg; ++g2) offv += gtot_s[g2 * 32 + e];
      float cacc = offv;
#pragma unroll
      for (int r = 0; r < 8; ++r) {
        cacc += vals[r];
        kc_s[(rg * 8 + r) * 36 + e] = cacc;   // kpre + cumsum_local(k)
      }
    }
    *(float4*)&q_s[j0 * 36 + cb]        = qA;   // overwrites dead qbf/kbf
    *(float4*)&q_s[(j0 + 32) * 36 + cb] = qB;
    __syncthreads();

    // ---- part 3: fp32 den (wave 0) + O MFMAs (all waves) ------------------
    if (t < 64) {
      int i = t;
      float dp = 0.f;
#pragma unroll
      for (int d4 = 0; d4 < 8; ++d4) {
        float4 qv = *(const float4*)&q_s[i * 36 + 4 * d4];
        float4 kc = *(const float4*)&kc_s[i * 36 + 4 * d4];
        dp += qv.x * kc.x + qv.y * kc.y + qv.z * kc.z + qv.w * kc.w;
      }
      invdiv_s[i] = 1.f / ((float)(c * C + i + 1) + dp);
    }
    f32x4 o0 = {0.f, 0.f, 0.f, 0.f}, o1 = {0.f, 0.f, 0.f, 0.f};
    {
      bf16x8 b0 = *(const bf16x8*)&kvTbf[(m16)      * 40 + quad * 8];
      bf16x8 b1 = *(const bf16x8*)&kvTbf[(16 + m16) * 40 + quad * 8];
      o0 = __builtin_amdgcn_mfma_f32_16x16x32_bf16(aQ, b0, o0, 0, 0, 0);
      o1 = __builtin_amdgcn_mfma_f32_16x16x32_bf16(aQ, b1, o1, 0, 0, 0);
    }
    int kbcnt = (w >= 2) ? 2 : 1;        // T zero past column 16w+15
    for (int kb2 = 0; kb2 < kbcnt; ++kb2) {
      bf16x8 aT = *(const bf16x8*)&Tbf[(16 * w + m16) * 72 + kb2 * 32 + quad * 8];
      bf16x8 b0 = *(const bf16x8*)&vTc[(m16)      * 72 + kb2 * 32 + quad * 8];
      bf16x8 b1 = *(const bf16x8*)&vTc[(16 + m16) * 72 + kb2 * 32 + quad * 8];
      o0 = __builtin_amdgcn_mfma_f32_16x16x32_bf16(aT, b0, o0, 0, 0, 0);
      o1 = __builtin_amdgcn_mfma_f32_16x16x32_bf16(aT, b1, o1, 0, 0, 0);
    }
    __syncthreads();

    // ---- epilogue: columns 2*m16, 2*m16+1 -> float2 stores ----------------
    int e0 = 2 * m16;
#pragma unroll
    for (int reg = 0; reg < 4; ++reg) {
      int i = 16 * w + quad * 4 + reg;
      float id = invdiv_s[i];
      float2 o;
      o.x = (pre_s[32 + e0]     + o0[reg]) * id;   // vsum prefix
      o.y = (pre_s[32 + e0 + 1] + o1[reg]) * id;
      *(float2*)&out[off + (size_t)i * D + e0] = o;
    }
    __syncthreads();                     // protect LDS before next restage

    qA = nqA; qB = nqB;
  }
}

// ---------------------------------------------------------------------------
extern "C" void kernel_launch(void* const* d_in, const int* in_sizes, int n_in,
                              void* d_out, int out_size, void* d_ws, size_t ws_size,
                              hipStream_t stream) {
  const float* q = (const float*)d_in[0];
  const float* k = (const float*)d_in[1];
  const float* v = (const float*)d_in[2];
  float* out = (float*)d_out;
  unsigned short* gtot = (unsigned short*)d_ws;               // 512*1152*2 = 1.2 MB
  unsigned int* flags =
      (unsigned int*)((char*)d_ws + (size_t)NGRP * AGGU * 2); // 2 KB

  hipMemsetAsync(flags, 0, NGRP * sizeof(unsigned int), stream);
  fused_kernel<<<NGRP, 256, 0, stream>>>(q, k, v, gtot, flags, out);
}

// Round 10
// 103.371 us; speedup vs baseline: 1.5346x; 1.5346x over previous
//
#include <hip/hip_runtime.h>

// fastmax linear attention (causal, p=1): chunked scan + bf16 MFMA matmuls.
// b=2, h=8, n=8192, d=32 -> bh=16, chunks of C=64 rows, 128 chunks per bh,
// 32 groups of 4 chunks per bh.  TWO plain launches -- measured best
// structure (R8: 103.7us).  Session-verified sync costs on gfx950:
// launch boundary ~8us < RMW-spin lookback ~40us < cg grid.sync ~50us/ea,
// so two launches beats every single-launch variant tried.
//  1) state_scan: 512 blocks, one per group of 4 chunks.  Depth-4 register
//     scan with global prefetch; writes each chunk's within-group EXCLUSIVE
//     KV prefix (pref: 1024 bf16 KV in [n][d1] MFMA staging layout + 64 fp32
//     ksum/vsum tail) and the group's INCLUSIVE total (gtot, same layout).
//  2) output: 512 blocks x 4 chunks.  The <=31-gtot lookback is hoisted once
//     per block (all 4 chunks share the group); next chunk's q/k/v/pref
//     register-prefetched under the MFMA section -> block-start latency paid
//     512x not 2048x, lookback traffic /4.  MFMA numerator + fp32
//     denominator.  LDS 37376B.

#define D      32
#define C      64
#define NCHUNK 128
#define GSIZE  4          // chunks per group == chunks per output block
#define NGROUP 32         // groups per bh
#define BH     16
#define NBLK   (BH * NCHUNK)     // 2048 chunks
#define NGRP   (NBLK / GSIZE)    // 512 groups
#define AGGU   1152   // ushorts per vector: 1024 bf16 KV + 64 fp32 tail

typedef __attribute__((ext_vector_type(8))) short bf16x8;
typedef __attribute__((ext_vector_type(4))) float f32x4;
typedef __attribute__((ext_vector_type(4))) unsigned short u16x4;

__device__ __forceinline__ unsigned short f2bf(float x) {
  union { float f; unsigned u; } c; c.f = x;
  unsigned r = (c.u + 0x7FFFu + ((c.u >> 16) & 1u)) >> 16;   // RNE
  return (unsigned short)r;
}
__device__ __forceinline__ float bf2f(unsigned short u) {
  union { unsigned u; float f; } c; c.u = ((unsigned)u) << 16;
  return c.f;
}
// MFMA output col n = original col (n<16 ? 2n : 2(n-16)+1); element with
// original col e stages at row n(e) = (e&1) ? 16+(e>>1) : (e>>1)
__device__ __forceinline__ int permcol(int e) {
  return (e & 1) ? (16 + (e >> 1)) : (e >> 1);
}

// ---------------------------------------------------------------------------
// Kernel 1: depth-4 per-group register scan.  grid = NGRP = 512.
// ---------------------------------------------------------------------------
__global__ __launch_bounds__(256) void state_scan_kernel(
    const float* __restrict__ k, const float* __restrict__ v,
    unsigned short* __restrict__ pref, unsigned short* __restrict__ gtot) {
  __shared__ __align__(16) unsigned short kT[D * 72];   // [e][j]
  __shared__ __align__(16) unsigned short vT[D * 72];   // [e][j]
  __shared__ __align__(16) float psK[1024];             // per-thread col partials
  __shared__ __align__(16) float psV[1024];

  int t  = threadIdx.x;
  int j0 = t >> 3;
  int cb = (t & 7) * 4;
  int lane = t & 63, w = t >> 6;
  int m16 = lane & 15, quad = lane >> 4;
  int mb = w >> 1, nb = w & 1;
  int d1b = 16 * mb + quad * 4;
  int np  = permcol(16 * nb + m16);      // staging row for this thread's col

  int c0 = blockIdx.x * GSIZE;           // first chunk of this group
  const float4* kp = (const float4*)k + (size_t)c0 * 512;
  const float4* vp = (const float4*)v + (size_t)c0 * 512;

  float pr[4] = {0.f, 0.f, 0.f, 0.f};    // running KV prefix (fp32)
  float tailpref = 0.f;                  // running ksum/vsum prefix (t<64)

  float4 kA = kp[t], kB = kp[t + 256];   // preload chunk 0
  float4 vA = vp[t], vB = vp[t + 256];

  for (int ci = 0; ci < GSIZE; ++ci) {
    {
      const float* ka = &kA.x; const float* kb = &kB.x;
      const float* va = &vA.x; const float* vb = &vB.x;
#pragma unroll
      for (int cc = 0; cc < 4; ++cc) {
        kT[(cb + cc) * 72 + j0]      = f2bf(ka[cc]);
        kT[(cb + cc) * 72 + j0 + 32] = f2bf(kb[cc]);
        vT[(cb + cc) * 72 + j0]      = f2bf(va[cc]);
        vT[(cb + cc) * 72 + j0 + 32] = f2bf(vb[cc]);
      }
      *(float4*)&psK[4 * t] =
          make_float4(kA.x + kB.x, kA.y + kB.y, kA.z + kB.z, kA.w + kB.w);
      *(float4*)&psV[4 * t] =
          make_float4(vA.x + vB.x, vA.y + vB.y, vA.z + vB.z, vA.w + vB.w);
    }
    __syncthreads();

    if (ci + 1 < GSIZE) {                // prefetch next chunk
      const float4* kn = kp + (size_t)(ci + 1) * 512;
      const float4* vn = vp + (size_t)(ci + 1) * 512;
      kA = kn[t]; kB = kn[t + 256];
      vA = vn[t]; vB = vn[t + 256];
    }

    // KV = K^T.V for this chunk (4 16x16 tiles across 4 waves)
    f32x4 acc = {0.f, 0.f, 0.f, 0.f};
#pragma unroll
    for (int kb2 = 0; kb2 < 2; ++kb2) {
      bf16x8 a = *(const bf16x8*)&kT[(16 * mb + m16) * 72 + kb2 * 32 + quad * 8];
      bf16x8 b = *(const bf16x8*)&vT[(16 * nb + m16) * 72 + kb2 * 32 + quad * 8];
      acc = __builtin_amdgcn_mfma_f32_16x16x32_bf16(a, b, acc, 0, 0, 0);
    }
    float csum = 0.f;
    if (t < 64) {
      int ee = t & 31;
      const float* ps = (t < 32) ? psK : psV;
#pragma unroll
      for (int m = 0; m < 32; ++m) csum += ps[ee + 32 * m];
    }

    // write EXCLUSIVE within-group prefix, then fold own aggregate
    unsigned short* pc = pref + (size_t)(c0 + ci) * AGGU;
    *(u16x4*)&pc[np * 32 + d1b] =
        (u16x4){f2bf(pr[0]), f2bf(pr[1]), f2bf(pr[2]), f2bf(pr[3])};
#pragma unroll
    for (int reg = 0; reg < 4; ++reg) pr[reg] += acc[reg];
    if (t < 64) {
      ((float*)(pc + 1024))[t] = tailpref;   // fp32 tail (den-critical!)
      tailpref += csum;
    }
    __syncthreads();                     // protect kT/vT/ps before restage
  }

  // INCLUSIVE group total
  unsigned short* gt = gtot + (size_t)blockIdx.x * AGGU;
  *(u16x4*)&gt[np * 32 + d1b] =
      (u16x4){f2bf(pr[0]), f2bf(pr[1]), f2bf(pr[2]), f2bf(pr[3])};
  if (t < 64) ((float*)(gt + 1024))[t] = tailpref;
}

// ---------------------------------------------------------------------------
// Kernel 2: MFMA output kernel.  grid = NGRP = 512 blocks, 4 chunks each.
// Lookback hoisted per block; q/k/v/pref prefetched across the chunk loop.
// ---------------------------------------------------------------------------
__global__ __launch_bounds__(256, 4) void output_kernel(
    const float* __restrict__ q, const float* __restrict__ k,
    const float* __restrict__ v, const unsigned short* __restrict__ pref,
    const unsigned short* __restrict__ gtot, float* __restrict__ out) {
  int g   = blockIdx.x & 31;             // group index within bh
  int bh  = blockIdx.x >> 5;
  int blk0 = blockIdx.x * GSIZE;         // first chunk of this block
  const float4* qp4 = (const float4*)q + (size_t)blk0 * 512;
  const float4* kp4 = (const float4*)k + (size_t)blk0 * 512;
  const float4* vp4 = (const float4*)v + (size_t)blk0 * 512;
  const unsigned short* prf = pref + (size_t)blk0 * AGGU;
  const unsigned short* gtb = gtot + (size_t)(bh * NGROUP) * AGGU;

  // union region: {qbf[64][40] | kbf[64][40]} during staging+part1;
  // q_s[64][36] fp32 (written in part2, read in part3) afterwards.
  __shared__ __align__(16) char uA[10240];
  unsigned short* qbf = (unsigned short*)uA;            // [i][dd]
  unsigned short* kbf = (unsigned short*)(uA + 5120);   // [j][dd]
  float* q_s = (float*)uA;                              // [i][dd] fp32, part2+
  __shared__ __align__(16) unsigned short vTbf[D * 72];   // [n][j] permuted cols
  __shared__ __align__(16) unsigned short kvTbf[D * 40];  // [n][dd] permuted cols
  __shared__ __align__(16) unsigned short Tbf[C * 72];    // [i][j]
  __shared__ __align__(16) float kc_s[C * 36];            // fp32 k -> cumsum+kpre
  __shared__ __align__(16) float gtot_s[8 * 32];
  __shared__ __align__(16) float pre_s[64];               // [0:32)=ksum, [32:64)=vsum
  __shared__ __align__(16) float invdiv_s[C];

  int t  = threadIdx.x;
  int j0 = t >> 3;
  int cb = (t & 7) * 4;
  int lane = t & 63, w = t >> 6;
  int m16 = lane & 15, quad = lane >> 4;
  int rg = t >> 5;                       // row-group 0..7
  int e  = t & 31;

  // ---- hoisted: sum of <=31 preceding group totals (shared by 4 chunks) ---
  float gs0 = 0.f, gs1 = 0.f, gs2 = 0.f, gs3 = 0.f, gtf = 0.f;
  for (int p0 = 0; p0 < g; p0 += 8) {    // <=4 rounds, 8 loads in flight each
    uint2 r[8]; float tl[8];
#pragma unroll
    for (int u = 0; u < 8; ++u) {
      int p = p0 + u;
      const unsigned short* gp = gtb + (size_t)(p < g ? p : 0) * AGGU;
      r[u] = *(const uint2*)&gp[4 * t];
      if (t < 64) tl[u] = ((const float*)(gp + 1024))[t];
    }
#pragma unroll
    for (int u = 0; u < 8; ++u) {
      if (p0 + u < g) {
        gs0 += bf2f((unsigned short)(r[u].x & 0xffff));
        gs1 += bf2f((unsigned short)(r[u].x >> 16));
        gs2 += bf2f((unsigned short)(r[u].y & 0xffff));
        gs3 += bf2f((unsigned short)(r[u].y >> 16));
        if (t < 64) gtf += tl[u];
      }
    }
  }

  // ---- preload chunk 0 ----------------------------------------------------
  float4 qA = qp4[t], qB = qp4[t + 256];
  float4 kA = kp4[t], kB = kp4[t + 256];
  float4 vA = vp4[t], vB = vp4[t + 256];
  uint2 rp = *(const uint2*)&prf[4 * t];
  float tlp = (t < 64) ? ((const float*)(prf + 1024))[t] : 0.f;

  for (int ci = 0; ci < GSIZE; ++ci) {
    int blk = blk0 + ci;
    int c   = blk & 127;
    size_t off = (size_t)blk * (C * D);

    // zero Tbf once: masked region stays zero across iterations (part 1
    // rewrites only its jb<=w tiles; jb>w tiles are never touched)
    if (ci == 0) {
      for (int z = t; z < (C * 72) / 8; z += 256)
        ((uint4*)Tbf)[z] = make_uint4(0, 0, 0, 0);
    }

    // ---- convert + stage (q_s deferred to part2: union with qbf/kbf) ------
    *(float4*)&kc_s[j0 * 36 + cb]        = kA;
    *(float4*)&kc_s[(j0 + 32) * 36 + cb] = kB;
    *(u16x4*)&qbf[j0 * 40 + cb] =
        (u16x4){f2bf(qA.x), f2bf(qA.y), f2bf(qA.z), f2bf(qA.w)};
    *(u16x4*)&qbf[(j0 + 32) * 40 + cb] =
        (u16x4){f2bf(qB.x), f2bf(qB.y), f2bf(qB.z), f2bf(qB.w)};
    *(u16x4*)&kbf[j0 * 40 + cb] =
        (u16x4){f2bf(kA.x), f2bf(kA.y), f2bf(kA.z), f2bf(kA.w)};
    *(u16x4*)&kbf[(j0 + 32) * 40 + cb] =
        (u16x4){f2bf(kB.x), f2bf(kB.y), f2bf(kB.z), f2bf(kB.w)};
    {
      const float* va = &vA.x; const float* vb = &vB.x;
#pragma unroll
      for (int cc = 0; cc < 4; ++cc) {
        int n = permcol(cb + cc);
        vTbf[n * 72 + j0]      = f2bf(va[cc]);
        vTbf[n * 72 + j0 + 32] = f2bf(vb[cc]);
      }
    }
    // KV prefix: hoisted group sum + per-chunk pref -> bf16 ([n][d1] linear)
    {
      float s0 = gs0 + bf2f((unsigned short)(rp.x & 0xffff));
      float s1 = gs1 + bf2f((unsigned short)(rp.x >> 16));
      float s2 = gs2 + bf2f((unsigned short)(rp.y & 0xffff));
      float s3 = gs3 + bf2f((unsigned short)(rp.y >> 16));
      *(u16x4*)&kvTbf[(t >> 3) * 40 + (t & 7) * 4] =
          (u16x4){f2bf(s0), f2bf(s1), f2bf(s2), f2bf(s3)};
    }
    if (t < 64) pre_s[t] = gtf + tlp;
    __syncthreads();

    // ---- prefetch next chunk while MFMAs run -------------------------------
    float4 nqA = make_float4(0,0,0,0), nqB = nqA, nkA = nqA, nkB = nqA,
           nvA = nqA, nvB = nqA;
    uint2 nrp = make_uint2(0, 0); float ntlp = 0.f;
    if (ci + 1 < GSIZE) {
      const float4* qn = qp4 + (size_t)(ci + 1) * 512;
      const float4* kn = kp4 + (size_t)(ci + 1) * 512;
      const float4* vn = vp4 + (size_t)(ci + 1) * 512;
      nqA = qn[t]; nqB = qn[t + 256];
      nkA = kn[t]; nkB = kn[t + 256];
      nvA = vn[t]; nvB = vn[t + 256];
      const unsigned short* pn = prf + (size_t)(ci + 1) * AGGU;
      nrp = *(const uint2*)&pn[4 * t];
      if (t < 64) ntlp = ((const float*)(pn + 1024))[t];
    }

    // ---- part 1: S tiles -> Tbf;  k col-sum phase a ------------------------
    const bf16x8 aQ = *(const bf16x8*)&qbf[(16 * w + m16) * 40 + quad * 8];
    for (int jb = 0; jb <= w; ++jb) {
      bf16x8 bK = *(const bf16x8*)&kbf[(16 * jb + m16) * 40 + quad * 8];
      f32x4 cS = {0.f, 0.f, 0.f, 0.f};
      cS = __builtin_amdgcn_mfma_f32_16x16x32_bf16(aQ, bK, cS, 0, 0, 0);
      int jcol = 16 * jb + m16;
#pragma unroll
      for (int reg = 0; reg < 4; ++reg) {
        int i = 16 * w + quad * 4 + reg;
        float tv = (jcol <= i) ? (1.f + cS[reg]) : 0.f;
        Tbf[i * 72 + jcol] = f2bf(tv);
      }
    }
    float vals[8];
    {
      float run = 0.f;
#pragma unroll
      for (int r = 0; r < 8; ++r) {
        vals[r] = kc_s[(rg * 8 + r) * 36 + e];
        run += vals[r];
      }
      gtot_s[rg * 32 + e] = run;
    }
    __syncthreads();                     // qbf/kbf dead past this point

    // ---- part 2: group offsets + kpre -> k-cumsum; stage q_s --------------
    {
      float offv = pre_s[e];             // ksum prefix
      for (int g2 = 0; g2 < rg; ++g2) offv += gtot_s[g2 * 32 + e];
      float cacc = offv;
#pragma unroll
      for (int r = 0; r < 8; ++r) {
        cacc += vals[r];
        kc_s[(rg * 8 + r) * 36 + e] = cacc;   // kpre + cumsum_local(k)
      }
    }
    *(float4*)&q_s[j0 * 36 + cb]        = qA;   // overwrites dead qbf/kbf
    *(float4*)&q_s[(j0 + 32) * 36 + cb] = qB;
    __syncthreads();

    // ---- part 3: fp32 den (wave 0) + O MFMAs (all waves) ------------------
    if (t < 64) {
      int i = t;
      float dp = 0.f;
#pragma unroll
      for (int d4 = 0; d4 < 8; ++d4) {
        float4 qv = *(const float4*)&q_s[i * 36 + 4 * d4];
        float4 kc = *(const float4*)&kc_s[i * 36 + 4 * d4];
        dp += qv.x * kc.x + qv.y * kc.y + qv.z * kc.z + qv.w * kc.w;
      }
      invdiv_s[i] = 1.f / ((float)(c * C + i + 1) + dp);
    }
    f32x4 o0 = {0.f, 0.f, 0.f, 0.f}, o1 = {0.f, 0.f, 0.f, 0.f};
    {
      bf16x8 b0 = *(const bf16x8*)&kvTbf[(m16)      * 40 + quad * 8];
      bf16x8 b1 = *(const bf16x8*)&kvTbf[(16 + m16) * 40 + quad * 8];
      o0 = __builtin_amdgcn_mfma_f32_16x16x32_bf16(aQ, b0, o0, 0, 0, 0);
      o1 = __builtin_amdgcn_mfma_f32_16x16x32_bf16(aQ, b1, o1, 0, 0, 0);
    }
    int kbcnt = (w >= 2) ? 2 : 1;        // T zero past column 16w+15
    for (int kb2 = 0; kb2 < kbcnt; ++kb2) {
      bf16x8 aT = *(const bf16x8*)&Tbf[(16 * w + m16) * 72 + kb2 * 32 + quad * 8];
      bf16x8 b0 = *(const bf16x8*)&vTbf[(m16)      * 72 + kb2 * 32 + quad * 8];
      bf16x8 b1 = *(const bf16x8*)&vTbf[(16 + m16) * 72 + kb2 * 32 + quad * 8];
      o0 = __builtin_amdgcn_mfma_f32_16x16x32_bf16(aT, b0, o0, 0, 0, 0);
      o1 = __builtin_amdgcn_mfma_f32_16x16x32_bf16(aT, b1, o1, 0, 0, 0);
    }
    __syncthreads();

    // ---- epilogue: columns 2*m16, 2*m16+1 -> float2 stores ----------------
    int e0 = 2 * m16;
#pragma unroll
    for (int reg = 0; reg < 4; ++reg) {
      int i = 16 * w + quad * 4 + reg;
      float id = invdiv_s[i];
      float2 o;
      o.x = (pre_s[32 + e0]     + o0[reg]) * id;   // vsum prefix
      o.y = (pre_s[32 + e0 + 1] + o1[reg]) * id;
      *(float2*)&out[off + (size_t)i * D + e0] = o;
    }
    __syncthreads();                     // protect LDS before next restage

    qA = nqA; qB = nqB; kA = nkA; kB = nkB; vA = nvA; vB = nvB;
    rp = nrp; tlp = ntlp;
  }
}

// ---------------------------------------------------------------------------
extern "C" void kernel_launch(void* const* d_in, const int* in_sizes, int n_in,
                              void* d_out, int out_size, void* d_ws, size_t ws_size,
                              hipStream_t stream) {
  const float* q = (const float*)d_in[0];
  const float* k = (const float*)d_in[1];
  const float* v = (const float*)d_in[2];
  float* out = (float*)d_out;
  unsigned short* pref = (unsigned short*)d_ws;                   // 4.7 MB
  unsigned short* gtot = pref + (size_t)NBLK * AGGU;              // 1.2 MB

  state_scan_kernel<<<NGRP, 256, 0, stream>>>(k, v, pref, gtot);
  output_kernel<<<NGRP, 256, 0, stream>>>(q, k, v, pref, gtot, out);
}